// Round 13
// baseline (206.383 us; speedup 1.0000x reference)
//
#include <hip/hip_runtime.h>
#include <math.h>

// Rod_Block: N=8, C_IN=64, C_OUT=128, G=4, CG=16, K=3, P=9, PAD=1, H=W=64.
// All tensors fp32. Padded spatial 66x66.
// Round-13: remove per-block LDS weight staging from k_xsproj (inp_w) and
// k_out (conv_w) — loads are coalesced + L1-broadcast, staging only cost
// occupancy + a barrier (round-9 lesson applied in the profitable direction).
// k_pool / k_dwsamp unchanged from round 12.

// ---- K1: pooled[n,c] = mean_{h,w} x[n,c,h,w]  (512 blocks x 256) ----
__global__ __launch_bounds__(256) void k_pool(const float* x, float* pooled) {
    __shared__ float red[256];
    int b = blockIdx.x;
    int nc = ((b & 7) << 6) | (b >> 3);     // n = b%8, c = b/8
    const float4* p4 = reinterpret_cast<const float4*>(x + (size_t)nc * 4096);
    float s = 0.f;
    for (int i = threadIdx.x; i < 1024; i += 256) {
        float4 v = p4[i];
        s += v.x + v.y + v.z + v.w;
    }
    red[threadIdx.x] = s;
    __syncthreads();
    for (int o = 128; o > 0; o >>= 1) {
        if (threadIdx.x < o) red[threadIdx.x] += red[threadIdx.x + o];
        __syncthreads();
    }
    if (threadIdx.x == 0) pooled[nc] = red[0] * (1.f / 4096.f);
}

// ---- K2: fused gain-MLP + xs(NHWC) + input_proj + xpad borders ----
// 2048 blocks x 256; block = (n=b%8, h, 16-wide w-chunk). No weight staging.
__global__ __launch_bounds__(256) void k_xsproj(
        const float* x, const float* refl,
        const float* tap_w, const float* tap_b,
        const float* pooled,
        const float* gw1, const float* gb1,
        const float* gw2, const float* gb2,
        const float* inp_w, const float* inp_b,
        float* xs, float* xpad) {
    __shared__ float tile[64 * 17];   // x [c][w] chunk, stride 17 (conflict-free)
    __shared__ float xsrow[16][68];   // xs [w][c] chunk
    __shared__ float hid[16];
    __shared__ float gain[64];
    __shared__ float rrow[16];
    int b = blockIdx.x;
    int n = b & 7, rem = b >> 3;            // XCD-locality swizzle
    int h = rem >> 2, wc = rem & 3, w0 = wc * 16;
    int nh = n * 64 + h;
    int tid = threadIdx.x;

    {   // x tile: c = tid>>2 (0..63), wq = tid&3 -> one float4 of 4 w's
        int c = tid >> 2, wq = (tid & 3) * 4;
        const float4 v = *reinterpret_cast<const float4*>(
            &x[(((size_t)(n * 64 + c)) * 64 + h) * 64 + w0 + wq]);
        tile[c * 17 + wq + 0] = v.x;
        tile[c * 17 + wq + 1] = v.y;
        tile[c * 17 + wq + 2] = v.z;
        tile[c * 17 + wq + 3] = v.w;
    }
    if (tid < 16) rrow[tid] = refl[n * 4096 + h * 64 + w0 + tid];
    if (tid >= 64 && tid < 80) {
        int j = tid - 64;
        float s = gb1[j];
        for (int c = 0; c < 64; ++c) s += pooled[n * 64 + c] * gw1[c * 16 + j];
        hid[j] = fmaxf(s, 0.f);
    }
    __syncthreads();

    if (tid < 64) {
        float s = gb2[tid];
        #pragma unroll
        for (int j = 0; j < 16; ++j) s += hid[j] * gw2[j * 64 + tid];
        gain[tid] = 1.f + 1.f / (1.f + expf(-s));
    }
    __syncthreads();

    // phase3: xs = x*(1+sig) + relu(refl*tapw+tapb); thread owns fixed c, 4 w's
    {
        int c = tid & 63, wbq = tid >> 6;    // w = wbq + k*4
        float gv = gain[c], tw = tap_w[c], tb = tap_b[c];
        #pragma unroll
        for (int k = 0; k < 4; ++k) {
            int w = wbq + k * 4;
            float r = fmaxf(rrow[w] * tw + tb, 0.f);
            float v = tile[c * 17 + w] * gv + r;
            xsrow[w][c] = v;
            xs[(((size_t)nh) * 64 + w0 + w) * 64 + c] = v;
        }
    }
    __syncthreads();

    // phase4: input_proj (direct coalesced inp_w loads + broadcast xsrow) -> xpad
    {
        int co = tid & 63, wg = tid >> 6;    // thread: 4 w's (wg*4..wg*4+3), one co
        float acc[4];
        float bv = inp_b[co];
        #pragma unroll
        for (int i = 0; i < 4; ++i) acc[i] = bv;
        for (int c4 = 0; c4 < 64; c4 += 4) {
            float q0 = inp_w[(c4 + 0) * 64 + co];
            float q1 = inp_w[(c4 + 1) * 64 + co];
            float q2 = inp_w[(c4 + 2) * 64 + co];
            float q3 = inp_w[(c4 + 3) * 64 + co];
            #pragma unroll
            for (int i = 0; i < 4; ++i) {
                float4 d = *reinterpret_cast<const float4*>(&xsrow[wg * 4 + i][c4]);
                acc[i] += d.x * q0 + d.y * q1 + d.z * q2 + d.w * q3;
            }
        }
        const size_t rowb = (((size_t)n * 66) + (h + 1)) * 66;
        #pragma unroll
        for (int i = 0; i < 4; ++i) {
            int w = wg * 4 + i;
            xpad[(rowb + (w0 + w + 1)) * 64 + co] = acc[i];
        }
        // borders: interior-row left/right columns
        if (wc == 0 && tid < 64) xpad[rowb * 64 + tid] = 0.f;
        if (wc == 3 && tid < 64) xpad[(rowb + 65) * 64 + tid] = 0.f;
        // top/bottom full rows (each chunk zeroes its 16 q's + corner blocks the ends)
        if (h == 0 || h == 63) {
            const size_t rb = (((size_t)n * 66) + (h == 0 ? 0 : 65)) * 66;
            for (int i = tid; i < 1024; i += 256) {
                int q = 1 + w0 + (i >> 6), cc = i & 63;
                xpad[(rb + q) * 64 + cc] = 0.f;
            }
            if (wc == 0 && tid < 64) xpad[rb * 64 + tid] = 0.f;
            if (wc == 3 && tid < 64) xpad[(rb + 65) * 64 + tid] = 0.f;
        }
    }
}

// ---- K3: fused dw3x3+LN+GELU -> off/mask proj -> softmax+coords -> bilinear -> outproj+BN1+ReLU
// 4096 blocks x 128 (2 waves); 4 px per wave, 8 px/block. n = blockIdx%8.
__global__ __launch_bounds__(128) void k_dwsamp(const float* xs, const float* xpad,
                       const float* dw_w, const float* dw_b,
                       const float* ln_g, const float* ln_b,
                       const float* off_w, const float* off_b,
                       const float* mask_w, const float* mask_b,
                       const float* outp_w, const float* outp_b,
                       const float* bn1_g, const float* bn1_b,
                       const float* bn1_m, const float* bn1_v,
                       float* vbuf) {
    __shared__ float  dwr[8][64];    // GELU(LN(dw)) per pixel
    __shared__ float  mlog[8][40];   // mask logits per pixel (36 used)
    __shared__ int4   sad[8][36];    // per (g,p): 4 clamped element offsets
    __shared__ float4 swt[8][36];    // per (g,p): validity*mask premultiplied weights
    __shared__ float  dcnl[8][64];   // sampled dcn per pixel

    int tid = threadIdx.x;
    int lane = tid & 63, wv = tid >> 6;      // wv in {0,1}
    int b = blockIdx.x;
    int n = b & 7;                           // XCD-locality swizzle
    int pos0 = (b >> 3) * 8 + wv * 4;        // wave's first pixel within image
    int h = pos0 >> 6, w0 = pos0 & 63;       // 4 consecutive w on one row
    int lbase = wv * 4;                      // local pixel base (0 or 4)
    int pbase = n * 4096 + pos0;

    // ---- Phase A: depthwise 3x3 (6-column shared halo) + LN + GELU, 4 pixels ----
    {
        float dwk[9];
        #pragma unroll
        for (int k = 0; k < 9; ++k) dwk[k] = dw_w[k * 64 + lane];
        float s[4];
        float bvv = dw_b[lane];
        #pragma unroll
        for (int p = 0; p < 4; ++p) s[p] = bvv;
        for (int ky = 0; ky < 3; ++ky) {
            int y = h + ky - 1;
            if (y < 0 || y > 63) continue;
            const float* xrow = xs + ((size_t)(n * 64 + y)) * 4096;
            float v[6];
            #pragma unroll
            for (int dx = 0; dx < 6; ++dx) {
                int x2 = w0 - 1 + dx;
                v[dx] = (x2 >= 0 && x2 <= 63) ? xrow[x2 * 64 + lane] : 0.f;
            }
            float k0 = dwk[ky * 3 + 0], k1 = dwk[ky * 3 + 1], k2 = dwk[ky * 3 + 2];
            #pragma unroll
            for (int p = 0; p < 4; ++p)
                s[p] += v[p] * k0 + v[p + 1] * k1 + v[p + 2] * k2;
        }
        float lngv = ln_g[lane], lnbv = ln_b[lane];
        #pragma unroll
        for (int p = 0; p < 4; ++p) {
            float sv = s[p];
            float sum = sv, sq = sv * sv;
            #pragma unroll
            for (int o = 32; o > 0; o >>= 1) {
                sum += __shfl_xor(sum, o, 64);
                sq  += __shfl_xor(sq,  o, 64);
            }
            float mu = sum * (1.f / 64.f);
            float var = sq * (1.f / 64.f) - mu * mu;
            float nrm = (sv - mu) * rsqrtf(var + 1e-6f) * lngv + lnbv;
            dwr[lbase + p][lane] = 0.5f * nrm * (1.f + erff(nrm * 0.70710678118654752f));
        }
    }
    __syncthreads();

    // ---- Phase B: 108 projections x 4 pixels; lane L<54 owns j={2L,2L+1}.
    // Offsets (L<36) stay in this lane's registers; mask logits (L 36..53) -> LDS.
    float a0[4], a1[4];
    {
        int jb = lane * 2;
        const float* wptr;
        int stride;
        float b0 = 0.f, b1 = 0.f;
        if (lane < 36)      { wptr = off_w + jb;         stride = 72; b0 = off_b[jb];       b1 = off_b[jb + 1]; }
        else if (lane < 54) { wptr = mask_w + (jb - 72); stride = 36; b0 = mask_b[jb - 72]; b1 = mask_b[jb - 71]; }
        else                { wptr = off_w;              stride = 0; }
        #pragma unroll
        for (int p = 0; p < 4; ++p) { a0[p] = b0; a1[p] = b1; }
        for (int c4 = 0; c4 < 64; c4 += 4) {
            float4 d0 = *reinterpret_cast<const float4*>(&dwr[lbase + 0][c4]);
            float4 d1 = *reinterpret_cast<const float4*>(&dwr[lbase + 1][c4]);
            float4 d2 = *reinterpret_cast<const float4*>(&dwr[lbase + 2][c4]);
            float4 d3 = *reinterpret_cast<const float4*>(&dwr[lbase + 3][c4]);
            float dk0[4] = {d0.x, d0.y, d0.z, d0.w};
            float dk1[4] = {d1.x, d1.y, d1.z, d1.w};
            float dk2[4] = {d2.x, d2.y, d2.z, d2.w};
            float dk3[4] = {d3.x, d3.y, d3.z, d3.w};
            #pragma unroll
            for (int k = 0; k < 4; ++k) {
                float2 w2 = *reinterpret_cast<const float2*>(wptr);
                wptr += stride;
                a0[0] += dk0[k] * w2.x;  a1[0] += dk0[k] * w2.y;
                a0[1] += dk1[k] * w2.x;  a1[1] += dk1[k] * w2.y;
                a0[2] += dk2[k] * w2.x;  a1[2] += dk2[k] * w2.y;
                a0[3] += dk3[k] * w2.x;  a1[3] += dk3[k] * w2.y;
            }
        }
        if (lane >= 36 && lane < 54) {
            int jm = lane * 2 - 72;           // 0..34 even
            #pragma unroll
            for (int p = 0; p < 4; ++p) {
                mlog[lbase + p][jm]     = a0[p];
                mlog[lbase + p][jm + 1] = a1[p];
            }
        }
    }
    __syncthreads();

    // ---- Phase B2 (lanes 0..35): softmax + sampling coords/weights per pixel.
    if (lane < 36) {
        int g = lane / 9, pp = lane - g * 9;
        #pragma unroll
        for (int p = 0; p < 4; ++p) {
            int li = lbase + p;
            const float* lrow = &mlog[li][g * 9];
            float m = lrow[0];
            #pragma unroll
            for (int k = 1; k < 9; ++k) m = fmaxf(m, lrow[k]);
            float ssum = 0.f, ek = 0.f;
            #pragma unroll
            for (int k = 0; k < 9; ++k) {
                float e = expf(lrow[k] - m);
                ssum += e;
                if (k == pp) ek = e;
            }
            float mk = ek / ssum;
            float px = (float)((w0 + p) + (pp / 3)) + a0[p];   // kernel grid w-outer/h-inner
            float py = (float)(h + (pp % 3)) + a1[p];
            float x0f = floorf(px), y0f = floorf(py);
            float wx = px - x0f, wy = py - y0f;
            int x0 = (int)x0f, y0 = (int)y0f;
            int x1 = x0 + 1, y1 = y0 + 1;
            int xc0 = min(max(x0, 0), 65), xc1 = min(max(x1, 0), 65);
            int yc0 = min(max(y0, 0), 65), yc1 = min(max(y1, 0), 65);
            float vx0 = (x0 >= 0 && x0 < 66) ? 1.f : 0.f;
            float vx1 = (x1 >= 0 && x1 < 66) ? 1.f : 0.f;
            float vy0 = (y0 >= 0 && y0 < 66) ? 1.f : 0.f;
            float vy1 = (y1 >= 0 && y1 < 66) ? 1.f : 0.f;
            float wx0 = (1.f - wx) * vx0, wx1 = wx * vx1;
            float wy0 = (1.f - wy) * vy0, wy1 = wy * vy1;
            swt[li][lane] = make_float4(mk * wy0 * wx0, mk * wy0 * wx1,
                                        mk * wy1 * wx0, mk * wy1 * wx1);
            sad[li][lane] = make_int4((yc0 * 66 + xc0) * 64, (yc0 * 66 + xc1) * 64,
                                      (yc1 * 66 + xc0) * 64, (yc1 * 66 + xc1) * 64);
        }
    }
    __syncthreads();

    // ---- Phase C: bilinear deformable sampling, branch-free, 4 pixels ----
    {
        int gb = (lane >> 4) * 9;
        const float* xpn = xpad + (size_t)n * 66 * 66 * 64;
        #pragma unroll
        for (int p = 0; p < 4; ++p) {
            int li = lbase + p;
            float acc = 0.f;
            #pragma unroll
            for (int pp = 0; pp < 9; ++pp) {
                int4   a  = sad[li][gb + pp];
                float4 cw = swt[li][gb + pp];
                acc += cw.x * xpn[a.x + lane] + cw.y * xpn[a.y + lane]
                     + cw.z * xpn[a.z + lane] + cw.w * xpn[a.w + lane];
            }
            dcnl[li][lane] = acc;
        }
    }
    __syncthreads();

    // ---- Phase D: output_proj + BN1 + ReLU, 4 pixels ----
    {
        float ob = outp_b[lane];
        float s0 = ob, s1 = ob, s2 = ob, s3 = ob;
        for (int c4 = 0; c4 < 64; c4 += 4) {
            float w0v = outp_w[(c4 + 0) * 64 + lane];
            float w1v = outp_w[(c4 + 1) * 64 + lane];
            float w2v = outp_w[(c4 + 2) * 64 + lane];
            float w3v = outp_w[(c4 + 3) * 64 + lane];
            float4 d0 = *reinterpret_cast<const float4*>(&dcnl[lbase + 0][c4]);
            float4 d1 = *reinterpret_cast<const float4*>(&dcnl[lbase + 1][c4]);
            float4 d2 = *reinterpret_cast<const float4*>(&dcnl[lbase + 2][c4]);
            float4 d3 = *reinterpret_cast<const float4*>(&dcnl[lbase + 3][c4]);
            s0 += d0.x * w0v + d0.y * w1v + d0.z * w2v + d0.w * w3v;
            s1 += d1.x * w0v + d1.y * w1v + d1.z * w2v + d1.w * w3v;
            s2 += d2.x * w0v + d2.y * w1v + d2.z * w2v + d2.w * w3v;
            s3 += d3.x * w0v + d3.y * w1v + d3.z * w2v + d3.w * w3v;
        }
        float sc = bn1_g[lane] * rsqrtf(bn1_v[lane] + 1e-5f);
        float sh = bn1_b[lane] - sc * bn1_m[lane];
        vbuf[(size_t)(pbase + 0) * 64 + lane] = fmaxf(sc * s0 + sh, 0.f);
        vbuf[(size_t)(pbase + 1) * 64 + lane] = fmaxf(sc * s1 + sh, 0.f);
        vbuf[(size_t)(pbase + 2) * 64 + lane] = fmaxf(sc * s2 + sh, 0.f);
        vbuf[(size_t)(pbase + 3) * 64 + lane] = fmaxf(sc * s3 + sh, 0.f);
    }
}

// ---- K4: 1x1 conv 64->128 + BN2 + ReLU, fp32 NCHW out ----
// 1024 blocks x 256; block = (n=b%8, h, d-half). Direct conv_w loads; LDS 17.4 KB.
__global__ __launch_bounds__(256) void k_out(const float* vbuf,
                      const float* conv_w, const float* conv_b,
                      const float* bn2_g, const float* bn2_b,
                      const float* bn2_m, const float* bn2_v,
                      float* out) {
    __shared__ float vl[64 * 68];   // [w][c], pad 68
    int b = blockIdx.x;
    int n = b & 7, rem = b >> 3;             // XCD-locality swizzle
    int h = rem >> 1, dh = (rem & 1) * 64;
    int tid = threadIdx.x;
    const float4* vrow4 = reinterpret_cast<const float4*>(vbuf + ((size_t)(n * 64 + h)) * 4096);
    for (int i = tid; i < 1024; i += 256) {
        int idx = i * 4;
        int w = idx >> 6, c = idx & 63;
        *reinterpret_cast<float4*>(&vl[w * 68 + c]) = vrow4[i];
    }
    __syncthreads();

    int dgrp = tid & 15, wgrp = tid >> 4;   // thread tile: 4 w x 4 d
    int dbase = dgrp * 4, wbase = wgrp * 4;
    float acc[4][4];
    #pragma unroll
    for (int i = 0; i < 4; ++i)
        #pragma unroll
        for (int j = 0; j < 4; ++j) acc[i][j] = 0.f;

    for (int c = 0; c < 64; ++c) {
        float v0 = vl[(wbase + 0) * 68 + c];
        float v1 = vl[(wbase + 1) * 68 + c];
        float v2 = vl[(wbase + 2) * 68 + c];
        float v3 = vl[(wbase + 3) * 68 + c];
        float4 wA = *reinterpret_cast<const float4*>(&conv_w[c * 128 + dh + dbase]);
        float wt[4] = {wA.x, wA.y, wA.z, wA.w};
        #pragma unroll
        for (int j = 0; j < 4; ++j) {
            acc[0][j] += v0 * wt[j];
            acc[1][j] += v1 * wt[j];
            acc[2][j] += v2 * wt[j];
            acc[3][j] += v3 * wt[j];
        }
    }

    #pragma unroll
    for (int j = 0; j < 4; ++j) {
        int d = dh + dbase + j;
        float sc = bn2_g[d] * rsqrtf(bn2_v[d] + 1e-5f);
        float sh = sc * (conv_b[d] - bn2_m[d]) + bn2_b[d];
        float4 r;
        r.x = fmaxf(sc * acc[0][j] + sh, 0.f);
        r.y = fmaxf(sc * acc[1][j] + sh, 0.f);
        r.z = fmaxf(sc * acc[2][j] + sh, 0.f);
        r.w = fmaxf(sc * acc[3][j] + sh, 0.f);
        size_t o = (((size_t)(n * 128 + d)) * 64 + h) * 64 + wbase;
        *reinterpret_cast<float4*>(out + o) = r;
    }
}

extern "C" void kernel_launch(void* const* d_in, const int* in_sizes, int n_in,
                              void* d_out, int out_size, void* d_ws, size_t ws_size,
                              hipStream_t stream) {
    const float* x      = (const float*)d_in[0];
    const float* refl   = (const float*)d_in[1];
    const float* gw1    = (const float*)d_in[2];
    const float* gb1    = (const float*)d_in[3];
    const float* gw2    = (const float*)d_in[4];
    const float* gb2    = (const float*)d_in[5];
    const float* tap_w  = (const float*)d_in[6];
    const float* tap_b  = (const float*)d_in[7];
    const float* dw_w   = (const float*)d_in[8];
    const float* dw_b   = (const float*)d_in[9];
    const float* ln_g   = (const float*)d_in[10];
    const float* ln_b   = (const float*)d_in[11];
    const float* inp_w  = (const float*)d_in[12];
    const float* inp_b  = (const float*)d_in[13];
    const float* off_w  = (const float*)d_in[14];
    const float* off_b  = (const float*)d_in[15];
    const float* mask_w = (const float*)d_in[16];
    const float* mask_b = (const float*)d_in[17];
    const float* outp_w = (const float*)d_in[18];
    const float* outp_b = (const float*)d_in[19];
    const float* conv_w = (const float*)d_in[20];
    const float* conv_b = (const float*)d_in[21];
    const float* bn1_g  = (const float*)d_in[22];
    const float* bn1_b  = (const float*)d_in[23];
    const float* bn1_m  = (const float*)d_in[24];
    const float* bn1_v  = (const float*)d_in[25];
    const float* bn2_g  = (const float*)d_in[26];
    const float* bn2_b  = (const float*)d_in[27];
    const float* bn2_m  = (const float*)d_in[28];
    const float* bn2_v  = (const float*)d_in[29];

    // workspace (floats): 512 + 2,097,152 + 2,230,272 + 2,097,152 ≈ 25.7 MiB
    float* ws     = (float*)d_ws;
    float* pooled = ws;                    // 512
    float* xs     = ws + 512;              // 2,097,152  (NHWC)
    float* xpad   = xs + 2097152;          // 2,230,272  (8*66*66*64, NHWC padded)
    float* vbuf   = xpad + 2230272;        // 2,097,152  (post BN1+ReLU, NHWC)

    k_pool<<<512, 256, 0, stream>>>(x, pooled);
    k_xsproj<<<2048, 256, 0, stream>>>(x, refl, tap_w, tap_b, pooled,
                                       gw1, gb1, gw2, gb2, inp_w, inp_b, xs, xpad);
    k_dwsamp<<<4096, 128, 0, stream>>>(xs, xpad, dw_w, dw_b, ln_g, ln_b,
                                       off_w, off_b, mask_w, mask_b,
                                       outp_w, outp_b, bn1_g, bn1_b, bn1_m, bn1_v, vbuf);
    k_out<<<1024, 256, 0, stream>>>(vbuf, conv_w, conv_b, bn2_g, bn2_b, bn2_m, bn2_v,
                                    (float*)d_out);
}

// Round 14
// 191.834 us; speedup vs baseline: 1.0758x; 1.0758x over previous
//
#include <hip/hip_runtime.h>
#include <math.h>

// Rod_Block: N=8, C_IN=64, C_OUT=128, G=4, CG=16, K=3, P=9, PAD=1, H=W=64.
// All tensors fp32. Padded spatial 66x66.
// Round-14: k_out FUSED into k_dwsamp as phase E (per-pixel 1x1 conv 64->128
// + BN2 + ReLU, lane=d/d+64, coalesced conv_w reads, float4 stores along w).
// Removes one launch + the 16 MB vbuf round-trip. expf -> __expf. 3 kernels.

// ---- K1: pooled[n,c] = mean_{h,w} x[n,c,h,w]  (512 blocks x 256) ----
__global__ __launch_bounds__(256) void k_pool(const float* x, float* pooled) {
    __shared__ float red[256];
    int b = blockIdx.x;
    int nc = ((b & 7) << 6) | (b >> 3);     // n = b%8, c = b/8
    const float4* p4 = reinterpret_cast<const float4*>(x + (size_t)nc * 4096);
    float s = 0.f;
    for (int i = threadIdx.x; i < 1024; i += 256) {
        float4 v = p4[i];
        s += v.x + v.y + v.z + v.w;
    }
    red[threadIdx.x] = s;
    __syncthreads();
    for (int o = 128; o > 0; o >>= 1) {
        if (threadIdx.x < o) red[threadIdx.x] += red[threadIdx.x + o];
        __syncthreads();
    }
    if (threadIdx.x == 0) pooled[nc] = red[0] * (1.f / 4096.f);
}

// ---- K2: fused gain-MLP + xs(NHWC) + input_proj + xpad borders ----
// 2048 blocks x 256; block = (n=b%8, h, 16-wide w-chunk).
__global__ __launch_bounds__(256) void k_xsproj(
        const float* x, const float* refl,
        const float* tap_w, const float* tap_b,
        const float* pooled,
        const float* gw1, const float* gb1,
        const float* gw2, const float* gb2,
        const float* inp_w, const float* inp_b,
        float* xs, float* xpad) {
    __shared__ float tile[64 * 17];   // x [c][w] chunk, stride 17 (conflict-free)
    __shared__ float xsrow[16][68];   // xs [w][c] chunk
    __shared__ float hid[16];
    __shared__ float gain[64];
    __shared__ float rrow[16];
    int b = blockIdx.x;
    int n = b & 7, rem = b >> 3;            // XCD-locality swizzle
    int h = rem >> 2, wc = rem & 3, w0 = wc * 16;
    int nh = n * 64 + h;
    int tid = threadIdx.x;

    {   // x tile: c = tid>>2 (0..63), wq = tid&3 -> one float4 of 4 w's
        int c = tid >> 2, wq = (tid & 3) * 4;
        const float4 v = *reinterpret_cast<const float4*>(
            &x[(((size_t)(n * 64 + c)) * 64 + h) * 64 + w0 + wq]);
        tile[c * 17 + wq + 0] = v.x;
        tile[c * 17 + wq + 1] = v.y;
        tile[c * 17 + wq + 2] = v.z;
        tile[c * 17 + wq + 3] = v.w;
    }
    if (tid < 16) rrow[tid] = refl[n * 4096 + h * 64 + w0 + tid];
    if (tid >= 64 && tid < 80) {
        int j = tid - 64;
        float s = gb1[j];
        for (int c = 0; c < 64; ++c) s += pooled[n * 64 + c] * gw1[c * 16 + j];
        hid[j] = fmaxf(s, 0.f);
    }
    __syncthreads();

    if (tid < 64) {
        float s = gb2[tid];
        #pragma unroll
        for (int j = 0; j < 16; ++j) s += hid[j] * gw2[j * 64 + tid];
        gain[tid] = 1.f + 1.f / (1.f + __expf(-s));
    }
    __syncthreads();

    // phase3: xs = x*(1+sig) + relu(refl*tapw+tapb); thread owns fixed c, 4 w's
    {
        int c = tid & 63, wbq = tid >> 6;    // w = wbq + k*4
        float gv = gain[c], tw = tap_w[c], tb = tap_b[c];
        #pragma unroll
        for (int k = 0; k < 4; ++k) {
            int w = wbq + k * 4;
            float r = fmaxf(rrow[w] * tw + tb, 0.f);
            float v = tile[c * 17 + w] * gv + r;
            xsrow[w][c] = v;
            xs[(((size_t)nh) * 64 + w0 + w) * 64 + c] = v;
        }
    }
    __syncthreads();

    // phase4: input_proj (direct coalesced inp_w loads + broadcast xsrow) -> xpad
    {
        int co = tid & 63, wg = tid >> 6;    // thread: 4 w's (wg*4..wg*4+3), one co
        float acc[4];
        float bv = inp_b[co];
        #pragma unroll
        for (int i = 0; i < 4; ++i) acc[i] = bv;
        for (int c4 = 0; c4 < 64; c4 += 4) {
            float q0 = inp_w[(c4 + 0) * 64 + co];
            float q1 = inp_w[(c4 + 1) * 64 + co];
            float q2 = inp_w[(c4 + 2) * 64 + co];
            float q3 = inp_w[(c4 + 3) * 64 + co];
            #pragma unroll
            for (int i = 0; i < 4; ++i) {
                float4 d = *reinterpret_cast<const float4*>(&xsrow[wg * 4 + i][c4]);
                acc[i] += d.x * q0 + d.y * q1 + d.z * q2 + d.w * q3;
            }
        }
        const size_t rowb = (((size_t)n * 66) + (h + 1)) * 66;
        #pragma unroll
        for (int i = 0; i < 4; ++i) {
            int w = wg * 4 + i;
            xpad[(rowb + (w0 + w + 1)) * 64 + co] = acc[i];
        }
        // borders: interior-row left/right columns
        if (wc == 0 && tid < 64) xpad[rowb * 64 + tid] = 0.f;
        if (wc == 3 && tid < 64) xpad[(rowb + 65) * 64 + tid] = 0.f;
        // top/bottom full rows
        if (h == 0 || h == 63) {
            const size_t rb = (((size_t)n * 66) + (h == 0 ? 0 : 65)) * 66;
            for (int i = tid; i < 1024; i += 256) {
                int q = 1 + w0 + (i >> 6), cc = i & 63;
                xpad[(rb + q) * 64 + cc] = 0.f;
            }
            if (wc == 0 && tid < 64) xpad[rb * 64 + tid] = 0.f;
            if (wc == 3 && tid < 64) xpad[(rb + 65) * 64 + tid] = 0.f;
        }
    }
}

// ---- K3: dw3x3+LN+GELU -> off/mask proj -> softmax+coords -> bilinear ->
//          outproj+BN1+ReLU -> 1x1 conv 64->128 + BN2 + ReLU (fused epilogue)
// 4096 blocks x 128 (2 waves); 4 px per wave, 8 px/block. n = blockIdx%8.
__global__ __launch_bounds__(128) void k_dwsamp(const float* xs, const float* xpad,
                       const float* dw_w, const float* dw_b,
                       const float* ln_g, const float* ln_b,
                       const float* off_w, const float* off_b,
                       const float* mask_w, const float* mask_b,
                       const float* outp_w, const float* outp_b,
                       const float* bn1_g, const float* bn1_b,
                       const float* bn1_m, const float* bn1_v,
                       const float* conv_w, const float* conv_b,
                       const float* bn2_g, const float* bn2_b,
                       const float* bn2_m, const float* bn2_v,
                       float* out) {
    __shared__ float  dwr[8][64];    // GELU(LN(dw)) per pixel
    __shared__ float  mlog[8][40];   // mask logits per pixel (36 used)
    __shared__ int4   sad[8][36];    // per (g,p): 4 clamped element offsets
    __shared__ float4 swt[8][36];    // per (g,p): validity*mask premultiplied weights
    __shared__ float  dcnl[8][64];   // phase C: sampled dcn; phase D overwrites with vbuf vals

    int tid = threadIdx.x;
    int lane = tid & 63, wv = tid >> 6;      // wv in {0,1}
    int b = blockIdx.x;
    int n = b & 7;                           // XCD-locality swizzle
    int pos0 = (b >> 3) * 8 + wv * 4;        // wave's first pixel within image
    int h = pos0 >> 6, w0 = pos0 & 63;       // 4 consecutive w on one row
    int lbase = wv * 4;                      // local pixel base (0 or 4)

    // ---- Phase A: depthwise 3x3 (6-column shared halo) + LN + GELU, 4 pixels ----
    {
        float dwk[9];
        #pragma unroll
        for (int k = 0; k < 9; ++k) dwk[k] = dw_w[k * 64 + lane];
        float s[4];
        float bvv = dw_b[lane];
        #pragma unroll
        for (int p = 0; p < 4; ++p) s[p] = bvv;
        for (int ky = 0; ky < 3; ++ky) {
            int y = h + ky - 1;
            if (y < 0 || y > 63) continue;
            const float* xrow = xs + ((size_t)(n * 64 + y)) * 4096;
            float v[6];
            #pragma unroll
            for (int dx = 0; dx < 6; ++dx) {
                int x2 = w0 - 1 + dx;
                v[dx] = (x2 >= 0 && x2 <= 63) ? xrow[x2 * 64 + lane] : 0.f;
            }
            float k0 = dwk[ky * 3 + 0], k1 = dwk[ky * 3 + 1], k2 = dwk[ky * 3 + 2];
            #pragma unroll
            for (int p = 0; p < 4; ++p)
                s[p] += v[p] * k0 + v[p + 1] * k1 + v[p + 2] * k2;
        }
        float lngv = ln_g[lane], lnbv = ln_b[lane];
        #pragma unroll
        for (int p = 0; p < 4; ++p) {
            float sv = s[p];
            float sum = sv, sq = sv * sv;
            #pragma unroll
            for (int o = 32; o > 0; o >>= 1) {
                sum += __shfl_xor(sum, o, 64);
                sq  += __shfl_xor(sq,  o, 64);
            }
            float mu = sum * (1.f / 64.f);
            float var = sq * (1.f / 64.f) - mu * mu;
            float nrm = (sv - mu) * rsqrtf(var + 1e-6f) * lngv + lnbv;
            dwr[lbase + p][lane] = 0.5f * nrm * (1.f + erff(nrm * 0.70710678118654752f));
        }
    }
    __syncthreads();

    // ---- Phase B: 108 projections x 4 pixels; lane L<54 owns j={2L,2L+1}.
    float a0[4], a1[4];
    {
        int jb = lane * 2;
        const float* wptr;
        int stride;
        float b0 = 0.f, b1 = 0.f;
        if (lane < 36)      { wptr = off_w + jb;         stride = 72; b0 = off_b[jb];       b1 = off_b[jb + 1]; }
        else if (lane < 54) { wptr = mask_w + (jb - 72); stride = 36; b0 = mask_b[jb - 72]; b1 = mask_b[jb - 71]; }
        else                { wptr = off_w;              stride = 0; }
        #pragma unroll
        for (int p = 0; p < 4; ++p) { a0[p] = b0; a1[p] = b1; }
        for (int c4 = 0; c4 < 64; c4 += 4) {
            float4 d0 = *reinterpret_cast<const float4*>(&dwr[lbase + 0][c4]);
            float4 d1 = *reinterpret_cast<const float4*>(&dwr[lbase + 1][c4]);
            float4 d2 = *reinterpret_cast<const float4*>(&dwr[lbase + 2][c4]);
            float4 d3 = *reinterpret_cast<const float4*>(&dwr[lbase + 3][c4]);
            float dk0[4] = {d0.x, d0.y, d0.z, d0.w};
            float dk1[4] = {d1.x, d1.y, d1.z, d1.w};
            float dk2[4] = {d2.x, d2.y, d2.z, d2.w};
            float dk3[4] = {d3.x, d3.y, d3.z, d3.w};
            #pragma unroll
            for (int k = 0; k < 4; ++k) {
                float2 w2 = *reinterpret_cast<const float2*>(wptr);
                wptr += stride;
                a0[0] += dk0[k] * w2.x;  a1[0] += dk0[k] * w2.y;
                a0[1] += dk1[k] * w2.x;  a1[1] += dk1[k] * w2.y;
                a0[2] += dk2[k] * w2.x;  a1[2] += dk2[k] * w2.y;
                a0[3] += dk3[k] * w2.x;  a1[3] += dk3[k] * w2.y;
            }
        }
        if (lane >= 36 && lane < 54) {
            int jm = lane * 2 - 72;           // 0..34 even
            #pragma unroll
            for (int p = 0; p < 4; ++p) {
                mlog[lbase + p][jm]     = a0[p];
                mlog[lbase + p][jm + 1] = a1[p];
            }
        }
    }
    __syncthreads();

    // ---- Phase B2 (lanes 0..35): softmax + sampling coords/weights per pixel ----
    if (lane < 36) {
        int g = lane / 9, pp = lane - g * 9;
        #pragma unroll
        for (int p = 0; p < 4; ++p) {
            int li = lbase + p;
            const float* lrow = &mlog[li][g * 9];
            float m = lrow[0];
            #pragma unroll
            for (int k = 1; k < 9; ++k) m = fmaxf(m, lrow[k]);
            float ssum = 0.f, ek = 0.f;
            #pragma unroll
            for (int k = 0; k < 9; ++k) {
                float e = __expf(lrow[k] - m);
                ssum += e;
                if (k == pp) ek = e;
            }
            float mk = ek / ssum;
            float px = (float)((w0 + p) + (pp / 3)) + a0[p];   // kernel grid w-outer/h-inner
            float py = (float)(h + (pp % 3)) + a1[p];
            float x0f = floorf(px), y0f = floorf(py);
            float wx = px - x0f, wy = py - y0f;
            int x0 = (int)x0f, y0 = (int)y0f;
            int x1 = x0 + 1, y1 = y0 + 1;
            int xc0 = min(max(x0, 0), 65), xc1 = min(max(x1, 0), 65);
            int yc0 = min(max(y0, 0), 65), yc1 = min(max(y1, 0), 65);
            float vx0 = (x0 >= 0 && x0 < 66) ? 1.f : 0.f;
            float vx1 = (x1 >= 0 && x1 < 66) ? 1.f : 0.f;
            float vy0 = (y0 >= 0 && y0 < 66) ? 1.f : 0.f;
            float vy1 = (y1 >= 0 && y1 < 66) ? 1.f : 0.f;
            float wx0 = (1.f - wx) * vx0, wx1 = wx * vx1;
            float wy0 = (1.f - wy) * vy0, wy1 = wy * vy1;
            swt[li][lane] = make_float4(mk * wy0 * wx0, mk * wy0 * wx1,
                                        mk * wy1 * wx0, mk * wy1 * wx1);
            sad[li][lane] = make_int4((yc0 * 66 + xc0) * 64, (yc0 * 66 + xc1) * 64,
                                      (yc1 * 66 + xc0) * 64, (yc1 * 66 + xc1) * 64);
        }
    }
    __syncthreads();

    // ---- Phase C: bilinear deformable sampling, branch-free, 4 pixels ----
    {
        int gb = (lane >> 4) * 9;
        const float* xpn = xpad + (size_t)n * 66 * 66 * 64;
        #pragma unroll
        for (int p = 0; p < 4; ++p) {
            int li = lbase + p;
            float acc = 0.f;
            #pragma unroll
            for (int pp = 0; pp < 9; ++pp) {
                int4   a  = sad[li][gb + pp];
                float4 cw = swt[li][gb + pp];
                acc += cw.x * xpn[a.x + lane] + cw.y * xpn[a.y + lane]
                     + cw.z * xpn[a.z + lane] + cw.w * xpn[a.w + lane];
            }
            dcnl[li][lane] = acc;
        }
    }
    __syncthreads();

    // ---- Phase D: output_proj + BN1 + ReLU -> overwrite dcnl with vbuf values ----
    // (wave-local: each wave reads/writes only its own 4 dcnl rows; lockstep makes
    //  the overwrite safe without a barrier)
    {
        float ob = outp_b[lane];
        float s0 = ob, s1 = ob, s2 = ob, s3 = ob;
        for (int c4 = 0; c4 < 64; c4 += 4) {
            float w0v = outp_w[(c4 + 0) * 64 + lane];
            float w1v = outp_w[(c4 + 1) * 64 + lane];
            float w2v = outp_w[(c4 + 2) * 64 + lane];
            float w3v = outp_w[(c4 + 3) * 64 + lane];
            float4 d0 = *reinterpret_cast<const float4*>(&dcnl[lbase + 0][c4]);
            float4 d1 = *reinterpret_cast<const float4*>(&dcnl[lbase + 1][c4]);
            float4 d2 = *reinterpret_cast<const float4*>(&dcnl[lbase + 2][c4]);
            float4 d3 = *reinterpret_cast<const float4*>(&dcnl[lbase + 3][c4]);
            s0 += d0.x * w0v + d0.y * w1v + d0.z * w2v + d0.w * w3v;
            s1 += d1.x * w0v + d1.y * w1v + d1.z * w2v + d1.w * w3v;
            s2 += d2.x * w0v + d2.y * w1v + d2.z * w2v + d2.w * w3v;
            s3 += d3.x * w0v + d3.y * w1v + d3.z * w2v + d3.w * w3v;
        }
        float sc = bn1_g[lane] * rsqrtf(bn1_v[lane] + 1e-5f);
        float sh = bn1_b[lane] - sc * bn1_m[lane];
        dcnl[lbase + 0][lane] = fmaxf(sc * s0 + sh, 0.f);
        dcnl[lbase + 1][lane] = fmaxf(sc * s1 + sh, 0.f);
        dcnl[lbase + 2][lane] = fmaxf(sc * s2 + sh, 0.f);
        dcnl[lbase + 3][lane] = fmaxf(sc * s3 + sh, 0.f);
    }
    // no barrier: phase E reads only this wave's own dcnl rows

    // ---- Phase E: 1x1 conv 64->128 + BN2 + ReLU; lane = d and d+64; float4 store along w ----
    {
        float accA[4], accB[4];   // [px] for d=lane, d=lane+64
        #pragma unroll
        for (int p = 0; p < 4; ++p) { accA[p] = 0.f; accB[p] = 0.f; }
        for (int c4 = 0; c4 < 64; c4 += 4) {
            float4 d0 = *reinterpret_cast<const float4*>(&dcnl[lbase + 0][c4]);
            float4 d1 = *reinterpret_cast<const float4*>(&dcnl[lbase + 1][c4]);
            float4 d2 = *reinterpret_cast<const float4*>(&dcnl[lbase + 2][c4]);
            float4 d3 = *reinterpret_cast<const float4*>(&dcnl[lbase + 3][c4]);
            float dk0[4] = {d0.x, d0.y, d0.z, d0.w};
            float dk1[4] = {d1.x, d1.y, d1.z, d1.w};
            float dk2[4] = {d2.x, d2.y, d2.z, d2.w};
            float dk3[4] = {d3.x, d3.y, d3.z, d3.w};
            #pragma unroll
            for (int k = 0; k < 4; ++k) {
                float wa = conv_w[(c4 + k) * 128 + lane];
                float wb = conv_w[(c4 + k) * 128 + 64 + lane];
                accA[0] += dk0[k] * wa;  accB[0] += dk0[k] * wb;
                accA[1] += dk1[k] * wa;  accB[1] += dk1[k] * wb;
                accA[2] += dk2[k] * wa;  accB[2] += dk2[k] * wb;
                accA[3] += dk3[k] * wa;  accB[3] += dk3[k] * wb;
            }
        }
        int dA = lane, dB = lane + 64;
        float scA = bn2_g[dA] * rsqrtf(bn2_v[dA] + 1e-5f);
        float shA = scA * (conv_b[dA] - bn2_m[dA]) + bn2_b[dA];
        float scB = bn2_g[dB] * rsqrtf(bn2_v[dB] + 1e-5f);
        float shB = scB * (conv_b[dB] - bn2_m[dB]) + bn2_b[dB];
        float4 rA, rB;
        rA.x = fmaxf(scA * accA[0] + shA, 0.f);
        rA.y = fmaxf(scA * accA[1] + shA, 0.f);
        rA.z = fmaxf(scA * accA[2] + shA, 0.f);
        rA.w = fmaxf(scA * accA[3] + shA, 0.f);
        rB.x = fmaxf(scB * accB[0] + shB, 0.f);
        rB.y = fmaxf(scB * accB[1] + shB, 0.f);
        rB.z = fmaxf(scB * accB[2] + shB, 0.f);
        rB.w = fmaxf(scB * accB[3] + shB, 0.f);
        size_t oA = (((size_t)(n * 128 + dA)) * 64 + h) * 64 + w0;
        size_t oB = (((size_t)(n * 128 + dB)) * 64 + h) * 64 + w0;
        *reinterpret_cast<float4*>(out + oA) = rA;
        *reinterpret_cast<float4*>(out + oB) = rB;
    }
}

extern "C" void kernel_launch(void* const* d_in, const int* in_sizes, int n_in,
                              void* d_out, int out_size, void* d_ws, size_t ws_size,
                              hipStream_t stream) {
    const float* x      = (const float*)d_in[0];
    const float* refl   = (const float*)d_in[1];
    const float* gw1    = (const float*)d_in[2];
    const float* gb1    = (const float*)d_in[3];
    const float* gw2    = (const float*)d_in[4];
    const float* gb2    = (const float*)d_in[5];
    const float* tap_w  = (const float*)d_in[6];
    const float* tap_b  = (const float*)d_in[7];
    const float* dw_w   = (const float*)d_in[8];
    const float* dw_b   = (const float*)d_in[9];
    const float* ln_g   = (const float*)d_in[10];
    const float* ln_b   = (const float*)d_in[11];
    const float* inp_w  = (const float*)d_in[12];
    const float* inp_b  = (const float*)d_in[13];
    const float* off_w  = (const float*)d_in[14];
    const float* off_b  = (const float*)d_in[15];
    const float* mask_w = (const float*)d_in[16];
    const float* mask_b = (const float*)d_in[17];
    const float* outp_w = (const float*)d_in[18];
    const float* outp_b = (const float*)d_in[19];
    const float* conv_w = (const float*)d_in[20];
    const float* conv_b = (const float*)d_in[21];
    const float* bn1_g  = (const float*)d_in[22];
    const float* bn1_b  = (const float*)d_in[23];
    const float* bn1_m  = (const float*)d_in[24];
    const float* bn1_v  = (const float*)d_in[25];
    const float* bn2_g  = (const float*)d_in[26];
    const float* bn2_b  = (const float*)d_in[27];
    const float* bn2_m  = (const float*)d_in[28];
    const float* bn2_v  = (const float*)d_in[29];

    // workspace (floats): 512 + 2,097,152 + 2,230,272 ≈ 17.3 MiB
    float* ws     = (float*)d_ws;
    float* pooled = ws;                    // 512
    float* xs     = ws + 512;              // 2,097,152  (NHWC)
    float* xpad   = xs + 2097152;          // 2,230,272  (8*66*66*64, NHWC padded)

    k_pool<<<512, 256, 0, stream>>>(x, pooled);
    k_xsproj<<<2048, 256, 0, stream>>>(x, refl, tap_w, tap_b, pooled,
                                       gw1, gb1, gw2, gb2, inp_w, inp_b, xs, xpad);
    k_dwsamp<<<4096, 128, 0, stream>>>(xs, xpad, dw_w, dw_b, ln_g, ln_b,
                                       off_w, off_b, mask_w, mask_b,
                                       outp_w, outp_b, bn1_g, bn1_b, bn1_m, bn1_v,
                                       conv_w, conv_b, bn2_g, bn2_b, bn2_m, bn2_v,
                                       (float*)d_out);
}

// Round 15
// 191.272 us; speedup vs baseline: 1.0790x; 1.0029x over previous
//
#include <hip/hip_runtime.h>
#include <math.h>

// Rod_Block: N=8, C_IN=64, C_OUT=128, G=4, CG=16, K=3, P=9, PAD=1, H=W=64.
// All tensors fp32. Padded spatial 66x66.
// Round-15: k_xsproj v3 — 128-thread blocks (2-wave barriers), 8-wide w-chunks,
// 4096 blocks (r12's dwsamp restructure applied to xsproj). k_pool / k_dwsamp
// byte-identical to round 14 (control).

// ---- K1: pooled[n,c] = mean_{h,w} x[n,c,h,w]  (512 blocks x 256) ----
__global__ __launch_bounds__(256) void k_pool(const float* x, float* pooled) {
    __shared__ float red[256];
    int b = blockIdx.x;
    int nc = ((b & 7) << 6) | (b >> 3);     // n = b%8, c = b/8
    const float4* p4 = reinterpret_cast<const float4*>(x + (size_t)nc * 4096);
    float s = 0.f;
    for (int i = threadIdx.x; i < 1024; i += 256) {
        float4 v = p4[i];
        s += v.x + v.y + v.z + v.w;
    }
    red[threadIdx.x] = s;
    __syncthreads();
    for (int o = 128; o > 0; o >>= 1) {
        if (threadIdx.x < o) red[threadIdx.x] += red[threadIdx.x + o];
        __syncthreads();
    }
    if (threadIdx.x == 0) pooled[nc] = red[0] * (1.f / 4096.f);
}

// ---- K2: fused gain-MLP + xs(NHWC) + input_proj + xpad borders ----
// 4096 blocks x 128; block = (n=b%8, h, 8-wide w-chunk).
__global__ __launch_bounds__(128) void k_xsproj(
        const float* x, const float* refl,
        const float* tap_w, const float* tap_b,
        const float* pooled,
        const float* gw1, const float* gb1,
        const float* gw2, const float* gb2,
        const float* inp_w, const float* inp_b,
        float* xs, float* xpad) {
    __shared__ float tile[64 * 9];    // x [c][w] chunk, stride 9 (conflict-free)
    __shared__ float xsrow[8][68];    // xs [w][c] chunk
    __shared__ float hid[16];
    __shared__ float gain[64];
    __shared__ float rrow[8];
    int b = blockIdx.x;
    int n = b & 7, rem = b >> 3;            // XCD-locality swizzle
    int h = rem >> 3, wc = rem & 7, w0 = wc * 8;
    int nh = n * 64 + h;
    int tid = threadIdx.x;

    {   // x tile: c = tid>>1 (0..63), wq = (tid&1)*4 -> one float4 of 4 w's
        int c = tid >> 1, wq = (tid & 1) * 4;
        const float4 v = *reinterpret_cast<const float4*>(
            &x[(((size_t)(n * 64 + c)) * 64 + h) * 64 + w0 + wq]);
        tile[c * 9 + wq + 0] = v.x;
        tile[c * 9 + wq + 1] = v.y;
        tile[c * 9 + wq + 2] = v.z;
        tile[c * 9 + wq + 3] = v.w;
    }
    if (tid < 8) rrow[tid] = refl[n * 4096 + h * 64 + w0 + tid];
    if (tid >= 64 && tid < 80) {
        int j = tid - 64;
        float s = gb1[j];
        for (int c = 0; c < 64; ++c) s += pooled[n * 64 + c] * gw1[c * 16 + j];
        hid[j] = fmaxf(s, 0.f);
    }
    __syncthreads();

    if (tid < 64) {
        float s = gb2[tid];
        #pragma unroll
        for (int j = 0; j < 16; ++j) s += hid[j] * gw2[j * 64 + tid];
        gain[tid] = 1.f + 1.f / (1.f + __expf(-s));
    }
    __syncthreads();

    // phase3: xs = x*(1+sig) + relu(refl*tapw+tapb); thread owns fixed c, 4 w's
    {
        int c = tid & 63, wg = tid >> 6;     // w = wg*4 + k
        float gv = gain[c], tw = tap_w[c], tb = tap_b[c];
        #pragma unroll
        for (int k = 0; k < 4; ++k) {
            int w = wg * 4 + k;
            float r = fmaxf(rrow[w] * tw + tb, 0.f);
            float v = tile[c * 9 + w] * gv + r;
            xsrow[w][c] = v;
            xs[(((size_t)nh) * 64 + w0 + w) * 64 + c] = v;
        }
    }
    __syncthreads();

    // phase4: input_proj (direct coalesced inp_w loads + broadcast xsrow) -> xpad
    {
        int co = tid & 63, wg = tid >> 6;    // thread: 4 w's (wg*4..wg*4+3), one co
        float acc[4];
        float bv = inp_b[co];
        #pragma unroll
        for (int i = 0; i < 4; ++i) acc[i] = bv;
        for (int c4 = 0; c4 < 64; c4 += 4) {
            float q0 = inp_w[(c4 + 0) * 64 + co];
            float q1 = inp_w[(c4 + 1) * 64 + co];
            float q2 = inp_w[(c4 + 2) * 64 + co];
            float q3 = inp_w[(c4 + 3) * 64 + co];
            #pragma unroll
            for (int i = 0; i < 4; ++i) {
                float4 d = *reinterpret_cast<const float4*>(&xsrow[wg * 4 + i][c4]);
                acc[i] += d.x * q0 + d.y * q1 + d.z * q2 + d.w * q3;
            }
        }
        const size_t rowb = (((size_t)n * 66) + (h + 1)) * 66;
        #pragma unroll
        for (int i = 0; i < 4; ++i) {
            int w = wg * 4 + i;
            xpad[(rowb + (w0 + w + 1)) * 64 + co] = acc[i];
        }
        // borders: interior-row left/right columns
        if (wc == 0 && tid < 64) xpad[rowb * 64 + tid] = 0.f;
        if (wc == 7 && tid < 64) xpad[(rowb + 65) * 64 + tid] = 0.f;
        // top/bottom full rows (each chunk zeroes its 8 q's; end chunks do corners)
        if (h == 0 || h == 63) {
            const size_t rb = (((size_t)n * 66) + (h == 0 ? 0 : 65)) * 66;
            for (int i = tid; i < 512; i += 128) {
                int q = 1 + w0 + (i >> 6), cc = i & 63;
                xpad[(rb + q) * 64 + cc] = 0.f;
            }
            if (wc == 0 && tid < 64) xpad[rb * 64 + tid] = 0.f;
            if (wc == 7 && tid < 64) xpad[(rb + 65) * 64 + tid] = 0.f;
        }
    }
}

// ---- K3: dw3x3+LN+GELU -> off/mask proj -> softmax+coords -> bilinear ->
//          outproj+BN1+ReLU -> 1x1 conv 64->128 + BN2 + ReLU (fused epilogue)
// 4096 blocks x 128 (2 waves); 4 px per wave, 8 px/block. n = blockIdx%8.
__global__ __launch_bounds__(128) void k_dwsamp(const float* xs, const float* xpad,
                       const float* dw_w, const float* dw_b,
                       const float* ln_g, const float* ln_b,
                       const float* off_w, const float* off_b,
                       const float* mask_w, const float* mask_b,
                       const float* outp_w, const float* outp_b,
                       const float* bn1_g, const float* bn1_b,
                       const float* bn1_m, const float* bn1_v,
                       const float* conv_w, const float* conv_b,
                       const float* bn2_g, const float* bn2_b,
                       const float* bn2_m, const float* bn2_v,
                       float* out) {
    __shared__ float  dwr[8][64];    // GELU(LN(dw)) per pixel
    __shared__ float  mlog[8][40];   // mask logits per pixel (36 used)
    __shared__ int4   sad[8][36];    // per (g,p): 4 clamped element offsets
    __shared__ float4 swt[8][36];    // per (g,p): validity*mask premultiplied weights
    __shared__ float  dcnl[8][64];   // phase C: sampled dcn; phase D overwrites with vbuf vals

    int tid = threadIdx.x;
    int lane = tid & 63, wv = tid >> 6;      // wv in {0,1}
    int b = blockIdx.x;
    int n = b & 7;                           // XCD-locality swizzle
    int pos0 = (b >> 3) * 8 + wv * 4;        // wave's first pixel within image
    int h = pos0 >> 6, w0 = pos0 & 63;       // 4 consecutive w on one row
    int lbase = wv * 4;                      // local pixel base (0 or 4)

    // ---- Phase A: depthwise 3x3 (6-column shared halo) + LN + GELU, 4 pixels ----
    {
        float dwk[9];
        #pragma unroll
        for (int k = 0; k < 9; ++k) dwk[k] = dw_w[k * 64 + lane];
        float s[4];
        float bvv = dw_b[lane];
        #pragma unroll
        for (int p = 0; p < 4; ++p) s[p] = bvv;
        for (int ky = 0; ky < 3; ++ky) {
            int y = h + ky - 1;
            if (y < 0 || y > 63) continue;
            const float* xrow = xs + ((size_t)(n * 64 + y)) * 4096;
            float v[6];
            #pragma unroll
            for (int dx = 0; dx < 6; ++dx) {
                int x2 = w0 - 1 + dx;
                v[dx] = (x2 >= 0 && x2 <= 63) ? xrow[x2 * 64 + lane] : 0.f;
            }
            float k0 = dwk[ky * 3 + 0], k1 = dwk[ky * 3 + 1], k2 = dwk[ky * 3 + 2];
            #pragma unroll
            for (int p = 0; p < 4; ++p)
                s[p] += v[p] * k0 + v[p + 1] * k1 + v[p + 2] * k2;
        }
        float lngv = ln_g[lane], lnbv = ln_b[lane];
        #pragma unroll
        for (int p = 0; p < 4; ++p) {
            float sv = s[p];
            float sum = sv, sq = sv * sv;
            #pragma unroll
            for (int o = 32; o > 0; o >>= 1) {
                sum += __shfl_xor(sum, o, 64);
                sq  += __shfl_xor(sq,  o, 64);
            }
            float mu = sum * (1.f / 64.f);
            float var = sq * (1.f / 64.f) - mu * mu;
            float nrm = (sv - mu) * rsqrtf(var + 1e-6f) * lngv + lnbv;
            dwr[lbase + p][lane] = 0.5f * nrm * (1.f + erff(nrm * 0.70710678118654752f));
        }
    }
    __syncthreads();

    // ---- Phase B: 108 projections x 4 pixels; lane L<54 owns j={2L,2L+1}.
    float a0[4], a1[4];
    {
        int jb = lane * 2;
        const float* wptr;
        int stride;
        float b0 = 0.f, b1 = 0.f;
        if (lane < 36)      { wptr = off_w + jb;         stride = 72; b0 = off_b[jb];       b1 = off_b[jb + 1]; }
        else if (lane < 54) { wptr = mask_w + (jb - 72); stride = 36; b0 = mask_b[jb - 72]; b1 = mask_b[jb - 71]; }
        else                { wptr = off_w;              stride = 0; }
        #pragma unroll
        for (int p = 0; p < 4; ++p) { a0[p] = b0; a1[p] = b1; }
        for (int c4 = 0; c4 < 64; c4 += 4) {
            float4 d0 = *reinterpret_cast<const float4*>(&dwr[lbase + 0][c4]);
            float4 d1 = *reinterpret_cast<const float4*>(&dwr[lbase + 1][c4]);
            float4 d2 = *reinterpret_cast<const float4*>(&dwr[lbase + 2][c4]);
            float4 d3 = *reinterpret_cast<const float4*>(&dwr[lbase + 3][c4]);
            float dk0[4] = {d0.x, d0.y, d0.z, d0.w};
            float dk1[4] = {d1.x, d1.y, d1.z, d1.w};
            float dk2[4] = {d2.x, d2.y, d2.z, d2.w};
            float dk3[4] = {d3.x, d3.y, d3.z, d3.w};
            #pragma unroll
            for (int k = 0; k < 4; ++k) {
                float2 w2 = *reinterpret_cast<const float2*>(wptr);
                wptr += stride;
                a0[0] += dk0[k] * w2.x;  a1[0] += dk0[k] * w2.y;
                a0[1] += dk1[k] * w2.x;  a1[1] += dk1[k] * w2.y;
                a0[2] += dk2[k] * w2.x;  a1[2] += dk2[k] * w2.y;
                a0[3] += dk3[k] * w2.x;  a1[3] += dk3[k] * w2.y;
            }
        }
        if (lane >= 36 && lane < 54) {
            int jm = lane * 2 - 72;           // 0..34 even
            #pragma unroll
            for (int p = 0; p < 4; ++p) {
                mlog[lbase + p][jm]     = a0[p];
                mlog[lbase + p][jm + 1] = a1[p];
            }
        }
    }
    __syncthreads();

    // ---- Phase B2 (lanes 0..35): softmax + sampling coords/weights per pixel ----
    if (lane < 36) {
        int g = lane / 9, pp = lane - g * 9;
        #pragma unroll
        for (int p = 0; p < 4; ++p) {
            int li = lbase + p;
            const float* lrow = &mlog[li][g * 9];
            float m = lrow[0];
            #pragma unroll
            for (int k = 1; k < 9; ++k) m = fmaxf(m, lrow[k]);
            float ssum = 0.f, ek = 0.f;
            #pragma unroll
            for (int k = 0; k < 9; ++k) {
                float e = __expf(lrow[k] - m);
                ssum += e;
                if (k == pp) ek = e;
            }
            float mk = ek / ssum;
            float px = (float)((w0 + p) + (pp / 3)) + a0[p];   // kernel grid w-outer/h-inner
            float py = (float)(h + (pp % 3)) + a1[p];
            float x0f = floorf(px), y0f = floorf(py);
            float wx = px - x0f, wy = py - y0f;
            int x0 = (int)x0f, y0 = (int)y0f;
            int x1 = x0 + 1, y1 = y0 + 1;
            int xc0 = min(max(x0, 0), 65), xc1 = min(max(x1, 0), 65);
            int yc0 = min(max(y0, 0), 65), yc1 = min(max(y1, 0), 65);
            float vx0 = (x0 >= 0 && x0 < 66) ? 1.f : 0.f;
            float vx1 = (x1 >= 0 && x1 < 66) ? 1.f : 0.f;
            float vy0 = (y0 >= 0 && y0 < 66) ? 1.f : 0.f;
            float vy1 = (y1 >= 0 && y1 < 66) ? 1.f : 0.f;
            float wx0 = (1.f - wx) * vx0, wx1 = wx * vx1;
            float wy0 = (1.f - wy) * vy0, wy1 = wy * vy1;
            swt[li][lane] = make_float4(mk * wy0 * wx0, mk * wy0 * wx1,
                                        mk * wy1 * wx0, mk * wy1 * wx1);
            sad[li][lane] = make_int4((yc0 * 66 + xc0) * 64, (yc0 * 66 + xc1) * 64,
                                      (yc1 * 66 + xc0) * 64, (yc1 * 66 + xc1) * 64);
        }
    }
    __syncthreads();

    // ---- Phase C: bilinear deformable sampling, branch-free, 4 pixels ----
    {
        int gb = (lane >> 4) * 9;
        const float* xpn = xpad + (size_t)n * 66 * 66 * 64;
        #pragma unroll
        for (int p = 0; p < 4; ++p) {
            int li = lbase + p;
            float acc = 0.f;
            #pragma unroll
            for (int pp = 0; pp < 9; ++pp) {
                int4   a  = sad[li][gb + pp];
                float4 cw = swt[li][gb + pp];
                acc += cw.x * xpn[a.x + lane] + cw.y * xpn[a.y + lane]
                     + cw.z * xpn[a.z + lane] + cw.w * xpn[a.w + lane];
            }
            dcnl[li][lane] = acc;
        }
    }
    __syncthreads();

    // ---- Phase D: output_proj + BN1 + ReLU -> overwrite dcnl with vbuf values ----
    {
        float ob = outp_b[lane];
        float s0 = ob, s1 = ob, s2 = ob, s3 = ob;
        for (int c4 = 0; c4 < 64; c4 += 4) {
            float w0v = outp_w[(c4 + 0) * 64 + lane];
            float w1v = outp_w[(c4 + 1) * 64 + lane];
            float w2v = outp_w[(c4 + 2) * 64 + lane];
            float w3v = outp_w[(c4 + 3) * 64 + lane];
            float4 d0 = *reinterpret_cast<const float4*>(&dcnl[lbase + 0][c4]);
            float4 d1 = *reinterpret_cast<const float4*>(&dcnl[lbase + 1][c4]);
            float4 d2 = *reinterpret_cast<const float4*>(&dcnl[lbase + 2][c4]);
            float4 d3 = *reinterpret_cast<const float4*>(&dcnl[lbase + 3][c4]);
            s0 += d0.x * w0v + d0.y * w1v + d0.z * w2v + d0.w * w3v;
            s1 += d1.x * w0v + d1.y * w1v + d1.z * w2v + d1.w * w3v;
            s2 += d2.x * w0v + d2.y * w1v + d2.z * w2v + d2.w * w3v;
            s3 += d3.x * w0v + d3.y * w1v + d3.z * w2v + d3.w * w3v;
        }
        float sc = bn1_g[lane] * rsqrtf(bn1_v[lane] + 1e-5f);
        float sh = bn1_b[lane] - sc * bn1_m[lane];
        dcnl[lbase + 0][lane] = fmaxf(sc * s0 + sh, 0.f);
        dcnl[lbase + 1][lane] = fmaxf(sc * s1 + sh, 0.f);
        dcnl[lbase + 2][lane] = fmaxf(sc * s2 + sh, 0.f);
        dcnl[lbase + 3][lane] = fmaxf(sc * s3 + sh, 0.f);
    }
    // no barrier: phase E reads only this wave's own dcnl rows

    // ---- Phase E: 1x1 conv 64->128 + BN2 + ReLU; lane = d and d+64; float4 store along w ----
    {
        float accA[4], accB[4];   // [px] for d=lane, d=lane+64
        #pragma unroll
        for (int p = 0; p < 4; ++p) { accA[p] = 0.f; accB[p] = 0.f; }
        for (int c4 = 0; c4 < 64; c4 += 4) {
            float4 d0 = *reinterpret_cast<const float4*>(&dcnl[lbase + 0][c4]);
            float4 d1 = *reinterpret_cast<const float4*>(&dcnl[lbase + 1][c4]);
            float4 d2 = *reinterpret_cast<const float4*>(&dcnl[lbase + 2][c4]);
            float4 d3 = *reinterpret_cast<const float4*>(&dcnl[lbase + 3][c4]);
            float dk0[4] = {d0.x, d0.y, d0.z, d0.w};
            float dk1[4] = {d1.x, d1.y, d1.z, d1.w};
            float dk2[4] = {d2.x, d2.y, d2.z, d2.w};
            float dk3[4] = {d3.x, d3.y, d3.z, d3.w};
            #pragma unroll
            for (int k = 0; k < 4; ++k) {
                float wa = conv_w[(c4 + k) * 128 + lane];
                float wb = conv_w[(c4 + k) * 128 + 64 + lane];
                accA[0] += dk0[k] * wa;  accB[0] += dk0[k] * wb;
                accA[1] += dk1[k] * wa;  accB[1] += dk1[k] * wb;
                accA[2] += dk2[k] * wa;  accB[2] += dk2[k] * wb;
                accA[3] += dk3[k] * wa;  accB[3] += dk3[k] * wb;
            }
        }
        int dA = lane, dB = lane + 64;
        float scA = bn2_g[dA] * rsqrtf(bn2_v[dA] + 1e-5f);
        float shA = scA * (conv_b[dA] - bn2_m[dA]) + bn2_b[dA];
        float scB = bn2_g[dB] * rsqrtf(bn2_v[dB] + 1e-5f);
        float shB = scB * (conv_b[dB] - bn2_m[dB]) + bn2_b[dB];
        float4 rA, rB;
        rA.x = fmaxf(scA * accA[0] + shA, 0.f);
        rA.y = fmaxf(scA * accA[1] + shA, 0.f);
        rA.z = fmaxf(scA * accA[2] + shA, 0.f);
        rA.w = fmaxf(scA * accA[3] + shA, 0.f);
        rB.x = fmaxf(scB * accB[0] + shB, 0.f);
        rB.y = fmaxf(scB * accB[1] + shB, 0.f);
        rB.z = fmaxf(scB * accB[2] + shB, 0.f);
        rB.w = fmaxf(scB * accB[3] + shB, 0.f);
        size_t oA = (((size_t)(n * 128 + dA)) * 64 + h) * 64 + w0;
        size_t oB = (((size_t)(n * 128 + dB)) * 64 + h) * 64 + w0;
        *reinterpret_cast<float4*>(out + oA) = rA;
        *reinterpret_cast<float4*>(out + oB) = rB;
    }
}

extern "C" void kernel_launch(void* const* d_in, const int* in_sizes, int n_in,
                              void* d_out, int out_size, void* d_ws, size_t ws_size,
                              hipStream_t stream) {
    const float* x      = (const float*)d_in[0];
    const float* refl   = (const float*)d_in[1];
    const float* gw1    = (const float*)d_in[2];
    const float* gb1    = (const float*)d_in[3];
    const float* gw2    = (const float*)d_in[4];
    const float* gb2    = (const float*)d_in[5];
    const float* tap_w  = (const float*)d_in[6];
    const float* tap_b  = (const float*)d_in[7];
    const float* dw_w   = (const float*)d_in[8];
    const float* dw_b   = (const float*)d_in[9];
    const float* ln_g   = (const float*)d_in[10];
    const float* ln_b   = (const float*)d_in[11];
    const float* inp_w  = (const float*)d_in[12];
    const float* inp_b  = (const float*)d_in[13];
    const float* off_w  = (const float*)d_in[14];
    const float* off_b  = (const float*)d_in[15];
    const float* mask_w = (const float*)d_in[16];
    const float* mask_b = (const float*)d_in[17];
    const float* outp_w = (const float*)d_in[18];
    const float* outp_b = (const float*)d_in[19];
    const float* conv_w = (const float*)d_in[20];
    const float* conv_b = (const float*)d_in[21];
    const float* bn1_g  = (const float*)d_in[22];
    const float* bn1_b  = (const float*)d_in[23];
    const float* bn1_m  = (const float*)d_in[24];
    const float* bn1_v  = (const float*)d_in[25];
    const float* bn2_g  = (const float*)d_in[26];
    const float* bn2_b  = (const float*)d_in[27];
    const float* bn2_m  = (const float*)d_in[28];
    const float* bn2_v  = (const float*)d_in[29];

    // workspace (floats): 512 + 2,097,152 + 2,230,272 ≈ 17.3 MiB
    float* ws     = (float*)d_ws;
    float* pooled = ws;                    // 512
    float* xs     = ws + 512;              // 2,097,152  (NHWC)
    float* xpad   = xs + 2097152;          // 2,230,272  (8*66*66*64, NHWC padded)

    k_pool<<<512, 256, 0, stream>>>(x, pooled);
    k_xsproj<<<4096, 128, 0, stream>>>(x, refl, tap_w, tap_b, pooled,
                                       gw1, gb1, gw2, gb2, inp_w, inp_b, xs, xpad);
    k_dwsamp<<<4096, 128, 0, stream>>>(xs, xpad, dw_w, dw_b, ln_g, ln_b,
                                       off_w, off_b, mask_w, mask_b,
                                       outp_w, outp_b, bn1_g, bn1_b, bn1_m, bn1_v,
                                       conv_w, conv_b, bn2_g, bn2_b, bn2_m, bn2_v,
                                       (float*)d_out);
}